// Round 1
// baseline (7230.370 us; speedup 1.0000x reference)
//
#include <hip/hip_runtime.h>

typedef unsigned short u16;
typedef unsigned int u32;
typedef __bf16 bf16x8 __attribute__((ext_vector_type(8)));
typedef float f32x4 __attribute__((ext_vector_type(4)));

#define B_ 256
#define T_ 128
#define E_ 300
#define EP 320
#define H_ 2048
#define G_ 8192

// ws layout (bytes)
#define OFF_XBF   0UL           // [T][B][EP] bf16           = 20,971,520
#define OFF_WPK   20971520UL    // 256 blk x 131072 B packed W_hh frags = 33,554,432
#define OFF_WIP   54525952UL    // 256 blk x 20480 B packed W_ih frags  =  5,242,880
#define OFF_BIAS  59768832UL    // 8192 f32                  = 32,768
#define OFF_HBUF  59801600UL    // 2 x [256][2048] bf16      = 2,097,152
#define OFF_BAR   61898752UL    // 128 u32

// plain global->LDS, 16B per lane, lane-linear dest
#define GLDS16(gp, sp)                                                    \
  __builtin_amdgcn_global_load_lds(                                       \
      (__attribute__((address_space(1))) void*)(void*)(gp),               \
      (__attribute__((address_space(3))) void*)(sp), 16, 0, 0)

__device__ __forceinline__ u16 f2bf(float f) {
  u32 u = __builtin_bit_cast(u32, f);
  return (u16)((u + 0x7FFFu + ((u >> 16) & 1u)) >> 16);
}
__device__ __forceinline__ float sigm_f(float x) {
  return __builtin_amdgcn_rcpf(1.0f + __expf(-x));
}
__device__ __forceinline__ float tanh_f(float x) {
  return 1.0f - 2.0f * __builtin_amdgcn_rcpf(1.0f + __expf(2.0f * x));
}

// ---------------- prep: pack/convert to bf16, fragment-order W, zero flags ----------------
// W_hh packed per block bid (8 h-cols j0=bid*8): [k2 0..63][f 0..1][lane 0..63][8 bf16]
//   lane l -> col n=l&15: gate = f*2 + (n>>3), c = n&7 ; k = k2*32 + (l>>4)*8 + e
// W_ih packed identically with k2 0..9 over EP=320 (zero-padded past E=300).
__global__ void prep_kernel(const float* __restrict__ x, const float* __restrict__ Wih,
                            const float* __restrict__ Whh, const float* __restrict__ bih,
                            const float* __restrict__ bhh, u16* __restrict__ xbf,
                            u16* __restrict__ wpk, u16* __restrict__ wip,
                            float* __restrict__ biasc, u32* __restrict__ bar) {
  const long NX = (long)T_ * B_ * EP;
  const long NWPK = 256L * 65536L;
  const long NWIP = 256L * 10240L;
  const long NBS = G_;
  const long NBAR = T_;
  const long total = NX + NWPK + NWIP + NBS + NBAR;
  for (long q = (long)blockIdx.x * blockDim.x + threadIdx.x; q < total;
       q += (long)gridDim.x * blockDim.x) {
    long r = q;
    if (r < NX) {
      int t = (int)(r / (B_ * EP));
      int rem = (int)(r % (B_ * EP));
      int b = rem / EP, e = rem % EP;
      float v = (e < E_) ? x[((long)b * T_ + t) * E_ + e] : 0.0f;
      xbf[r] = f2bf(v);
    } else if ((r -= NX) < NWPK) {
      int blk = (int)(r >> 16);
      int qq = (int)(r & 65535);
      int e = qq & 7, ln = (qq >> 3) & 63, f = (qq >> 9) & 1, k2 = qq >> 10;
      int gate = f * 2 + ((ln >> 3) & 1);
      int grow = gate * H_ + blk * 8 + (ln & 7);
      int k = k2 * 32 + ((ln >> 4) & 3) * 8 + e;
      wpk[r] = f2bf(Whh[(long)grow * H_ + k]);
    } else if ((r -= NWPK) < NWIP) {
      int blk = (int)(r / 10240);
      int qq = (int)(r % 10240);
      int e = qq & 7, ln = (qq >> 3) & 63, f = (qq >> 9) & 1, k2 = qq >> 10;
      int gate = f * 2 + ((ln >> 3) & 1);
      int grow = gate * H_ + blk * 8 + (ln & 7);
      int k = k2 * 32 + ((ln >> 4) & 3) * 8 + e;
      wip[r] = f2bf((k < E_) ? Wih[(long)grow * E_ + k] : 0.0f);
    } else if ((r -= NWIP) < NBS) {
      biasc[r] = bih[r] + bhh[r];
    } else {
      r -= NBS;
      bar[r] = 0;
    }
  }
}

// ---------------- main persistent LSTM kernel ----------------
// 256 blocks x 256 thr, 1 block/CU. Block bid owns 8 h-cols (j0=bid*8), i.e.
// 32 gate-rows x K=2048 of W_hh = 128 KiB: RESIDENT IN LDS for all 128 steps
// (plus 20 KiB W_ih slice). Zero W traffic in steady state.
// A operand (x_t, then h_t): all 256 batch rows, wave w owns rows w*64..w*64+63,
// MFMA fragments gathered DIRECT global->VGPR (L2-cached broadcast; each h byte
// hits L2 32x per XCD). No per-chunk __syncthreads at all: per step only the
// global h-barrier + one agent-acquire fence (buffer_inv) to drop stale h from
// L1/L2; producers write h via sc0sc1 write-through as before.
__global__ void __launch_bounds__(256, 1)
lstm_kernel(const u16* __restrict__ xbf, const u16* __restrict__ wpk,
            const u16* __restrict__ wip, const float* __restrict__ biasc,
            u16* __restrict__ hbuf, u32* __restrict__ bar, float* __restrict__ out) {
  __shared__ __align__(16) u16 Wl[65536];   // 128 KiB W_hh tile, frag-linear
  __shared__ __align__(16) u16 WIl[10240];  // 20 KiB  W_ih tile, frag-linear

  const int tid = threadIdx.x;
  const int l = tid & 63;
  const int w = tid >> 6;
  const int bid = blockIdx.x;
  const int rowbase = w << 6;        // wave's 64 batch rows
  const int rl = l & 15;             // fragment row lane
  const int kb = (l >> 4) << 3;      // k-offset within 32-k chunk
  const int c = l & 7;               // h-col within block
  const int jc = (bid << 3) + c;     // global h-col
  const int half = (l >> 3) & 1;     // 0: lane holds {i,g}; 1: lane holds {f,o}

  // ---- one-time stage of resident W tiles (frag-linear => lane-linear GLDS) ----
  {
    const u16* wsrc = wpk + ((size_t)bid << 16);
    const u16* wisrc = wip + (size_t)bid * 10240;
    u16* wdst = Wl + (w << 9);     // wave-uniform base; HW adds lane*16B
    u16* widst = WIl + (w << 9);
#pragma unroll
    for (int i = 0; i < 32; ++i)
      GLDS16(wsrc + (i << 11) + (tid << 3), wdst + (i << 11));
#pragma unroll
    for (int i = 0; i < 5; ++i)
      GLDS16(wisrc + (i << 11) + (tid << 3), widst + (i << 11));
    __syncthreads();
  }

  const float bi = biasc[jc];
  const float bff = biasc[H_ + jc];
  const float bg = biasc[2 * H_ + jc];
  const float bo = biasc[3 * H_ + jc];

  float cst[4][4];
#pragma unroll
  for (int rf = 0; rf < 4; ++rf)
#pragma unroll
    for (int r = 0; r < 4; ++r) cst[rf][r] = 0.0f;

#pragma unroll 1
  for (int t = 0; t < T_; ++t) {
    const u16* hcur = hbuf + (size_t)(t & 1) * (B_ * H_);
    u16* hnxt = hbuf + (size_t)((t + 1) & 1) * (B_ * H_);

    f32x4 acc[4][2];
#pragma unroll
    for (int rf = 0; rf < 4; ++rf) {
      acc[rf][0] = (f32x4){0.f, 0.f, 0.f, 0.f};
      acc[rf][1] = (f32x4){0.f, 0.f, 0.f, 0.f};
    }

    // ---- x phase (no h dependency): before barrier wait, hides producer skew
    {
      const u16* xa = xbf + (size_t)t * (B_ * EP) + (size_t)(rowbase + rl) * EP + kb;
#pragma unroll 2
      for (int k2 = 0; k2 < 10; ++k2) {
        bf16x8 b0 = *(const bf16x8*)(WIl + (k2 << 10) + (l << 3));
        bf16x8 b1 = *(const bf16x8*)(WIl + (k2 << 10) + 512 + (l << 3));
        bf16x8 a0 = *(const bf16x8*)(xa + (k2 << 5));
        bf16x8 a1 = *(const bf16x8*)(xa + 16 * EP + (k2 << 5));
        bf16x8 a2 = *(const bf16x8*)(xa + 32 * EP + (k2 << 5));
        bf16x8 a3 = *(const bf16x8*)(xa + 48 * EP + (k2 << 5));
        acc[0][0] = __builtin_amdgcn_mfma_f32_16x16x32_bf16(a0, b0, acc[0][0], 0, 0, 0);
        acc[0][1] = __builtin_amdgcn_mfma_f32_16x16x32_bf16(a0, b1, acc[0][1], 0, 0, 0);
        acc[1][0] = __builtin_amdgcn_mfma_f32_16x16x32_bf16(a1, b0, acc[1][0], 0, 0, 0);
        acc[1][1] = __builtin_amdgcn_mfma_f32_16x16x32_bf16(a1, b1, acc[1][1], 0, 0, 0);
        acc[2][0] = __builtin_amdgcn_mfma_f32_16x16x32_bf16(a2, b0, acc[2][0], 0, 0, 0);
        acc[2][1] = __builtin_amdgcn_mfma_f32_16x16x32_bf16(a2, b1, acc[2][1], 0, 0, 0);
        acc[3][0] = __builtin_amdgcn_mfma_f32_16x16x32_bf16(a3, b0, acc[3][0], 0, 0, 0);
        acc[3][1] = __builtin_amdgcn_mfma_f32_16x16x32_bf16(a3, b1, acc[3][1], 0, 0, 0);
      }
    }

    // ---- h phase (skipped at t=0: h==0)
    if (t > 0) {
      if (tid == 0) {
        while (__hip_atomic_load(&bar[t - 1], __ATOMIC_RELAXED,
                                 __HIP_MEMORY_SCOPE_AGENT) < 256u)
          __builtin_amdgcn_s_sleep(2);
      }
      __syncthreads();
      // drop stale h lines from L1/L2 so cached loads see L3-fresh data;
      // cheap now: nothing persistent lives in L2 (W is in LDS)
      __builtin_amdgcn_fence(__ATOMIC_ACQUIRE, "agent");

      const u16* ha = hcur + (size_t)(rowbase + rl) * H_ + kb;
#pragma unroll 4
      for (int k2 = 0; k2 < 64; ++k2) {
        bf16x8 b0 = *(const bf16x8*)(Wl + (k2 << 10) + (l << 3));
        bf16x8 b1 = *(const bf16x8*)(Wl + (k2 << 10) + 512 + (l << 3));
        bf16x8 a0 = *(const bf16x8*)(ha + (k2 << 5));
        bf16x8 a1 = *(const bf16x8*)(ha + 16 * H_ + (k2 << 5));
        bf16x8 a2 = *(const bf16x8*)(ha + 32 * H_ + (k2 << 5));
        bf16x8 a3 = *(const bf16x8*)(ha + 48 * H_ + (k2 << 5));
        acc[0][0] = __builtin_amdgcn_mfma_f32_16x16x32_bf16(a0, b0, acc[0][0], 0, 0, 0);
        acc[0][1] = __builtin_amdgcn_mfma_f32_16x16x32_bf16(a0, b1, acc[0][1], 0, 0, 0);
        acc[1][0] = __builtin_amdgcn_mfma_f32_16x16x32_bf16(a1, b0, acc[1][0], 0, 0, 0);
        acc[1][1] = __builtin_amdgcn_mfma_f32_16x16x32_bf16(a1, b1, acc[1][1], 0, 0, 0);
        acc[2][0] = __builtin_amdgcn_mfma_f32_16x16x32_bf16(a2, b0, acc[2][0], 0, 0, 0);
        acc[2][1] = __builtin_amdgcn_mfma_f32_16x16x32_bf16(a2, b1, acc[2][1], 0, 0, 0);
        acc[3][0] = __builtin_amdgcn_mfma_f32_16x16x32_bf16(a3, b0, acc[3][0], 0, 0, 0);
        acc[3][1] = __builtin_amdgcn_mfma_f32_16x16x32_bf16(a3, b1, acc[3][1], 0, 0, 0);
      }
    }

    // ---- pointwise: acc frag0 = {i|f}(c), frag1 = {g|o}(c); partner lane l^8
    // holds the complementary gates for the same (row, c). One shfl_xor pair
    // per acc element re-unites all 4 gates; both halves compute h redundantly.
#pragma unroll
    for (int rf = 0; rf < 4; ++rf) {
#pragma unroll
      for (int r = 0; r < 4; ++r) {
        float v0 = acc[rf][0][r];
        float v1 = acc[rf][1][r];
        float p0 = __shfl_xor(v0, 8);
        float p1 = __shfl_xor(v1, 8);
        float iv = half ? p0 : v0;
        float fv = half ? v0 : p0;
        float gv = half ? p1 : v1;
        float ov = half ? v1 : p1;
        float ig = sigm_f(iv + bi);
        float fg = sigm_f(fv + bff);
        float gg = tanh_f(gv + bg);
        float og = sigm_f(ov + bo);
        float cc = fg * cst[rf][r] + ig * gg;
        cst[rf][r] = cc;
        float h = og * tanh_f(cc);
        int row = rowbase + (rf << 4) + ((l >> 4) << 2) + r;
        if (t < T_ - 1) {
          if ((l & 8) == 0) {
            u16 hv = f2bf(h);
            u16* hp = hnxt + (size_t)row * H_ + jc;
            asm volatile("global_store_short %0, %1, off sc0 sc1"
                         :: "v"(hp), "v"((u32)hv) : "memory");
          }
        } else {
          if ((l & 8) == 0) out[(size_t)row * H_ + jc] = h;
        }
      }
    }

    if (t < T_ - 1) {
      __builtin_amdgcn_s_waitcnt(0);      // h stores reached coherent point (L3)
      __syncthreads();                    // all 4 waves drained
      if (tid == 0)
        __hip_atomic_fetch_add(&bar[t], 1u, __ATOMIC_RELAXED,
                               __HIP_MEMORY_SCOPE_AGENT);
    }
  }
}

extern "C" void kernel_launch(void* const* d_in, const int* in_sizes, int n_in,
                              void* d_out, int out_size, void* d_ws, size_t ws_size,
                              hipStream_t stream) {
  const float* x = (const float*)d_in[0];
  const float* Wih = (const float*)d_in[1];
  const float* Whh = (const float*)d_in[2];
  const float* bih = (const float*)d_in[3];
  const float* bhh = (const float*)d_in[4];
  char* ws = (char*)d_ws;
  u16* xbf = (u16*)(ws + OFF_XBF);
  u16* wpk = (u16*)(ws + OFF_WPK);
  u16* wip = (u16*)(ws + OFF_WIP);
  float* biasc = (float*)(ws + OFF_BIAS);
  u16* hbuf = (u16*)(ws + OFF_HBUF);
  u32* bar = (u32*)(ws + OFF_BAR);
  float* out = (float*)d_out;

  hipLaunchKernelGGL(prep_kernel, dim3(2048), dim3(256), 0, stream,
                     x, Wih, Whh, bih, bhh, xbf, wpk, wip, biasc, bar);

  void* args[] = {(void*)&xbf, (void*)&wpk, (void*)&wip,
                  (void*)&biasc, (void*)&hbuf, (void*)&bar, (void*)&out};
  hipLaunchCooperativeKernel((void*)lstm_kernel, dim3(256), dim3(256), args, 0, stream);
}

// Round 2
// 3727.644 us; speedup vs baseline: 1.9397x; 1.9397x over previous
//
#include <hip/hip_runtime.h>

typedef unsigned short u16;
typedef unsigned int u32;
typedef __bf16 bf16x8 __attribute__((ext_vector_type(8)));
typedef float f32x4 __attribute__((ext_vector_type(4)));

#define B_ 256
#define T_ 128
#define E_ 300
#define EP 320
#define H_ 2048
#define G_ 8192

// ws layout (bytes)
#define OFF_XBF   0UL
#define OFF_WIH   20971520UL
#define OFF_WHH   26214400UL
#define OFF_BIAS  59768832UL
#define OFF_HBUF  59801600UL
#define OFF_BAR   61898752UL

// plain global->LDS (L2-cacheable: weights, x)
#define GLDS16(gp, sp)                                                    \
  __builtin_amdgcn_global_load_lds(                                       \
      (__attribute__((address_space(1))) void*)(void*)(gp),               \
      (__attribute__((address_space(3))) void*)(sp), 16, 0, 0)
// device-coherent global->LDS (sc0|sc1: bypass L1+L2) for h
#define GLDS16C(gp, sp)                                                   \
  __builtin_amdgcn_global_load_lds(                                       \
      (__attribute__((address_space(1))) void*)(void*)(gp),               \
      (__attribute__((address_space(3))) void*)(sp), 16, 0, 17)

__device__ __forceinline__ u16 f2bf(float f) {
  u32 u = __builtin_bit_cast(u32, f);
  return (u16)((u + 0x7FFFu + ((u >> 16) & 1u)) >> 16);
}
__device__ __forceinline__ float sigm_f(float x) {
  return __builtin_amdgcn_rcpf(1.0f + __expf(-x));
}
__device__ __forceinline__ float tanh_f(float x) {
  return 1.0f - 2.0f * __builtin_amdgcn_rcpf(1.0f + __expf(2.0f * x));
}

// ---------------- prep: pack/convert to bf16, zero barrier flags ----------------
__global__ void prep_kernel(const float* __restrict__ x, const float* __restrict__ Wih,
                            const float* __restrict__ Whh, const float* __restrict__ bih,
                            const float* __restrict__ bhh, u16* __restrict__ xbf,
                            u16* __restrict__ wihb, u16* __restrict__ whhb,
                            float* __restrict__ biasc, u32* __restrict__ bar) {
  const long NX = (long)T_ * B_ * EP;
  const long NWIH = (long)G_ * EP;
  const long NWHH = (long)G_ * H_;
  const long NBS = G_;
  const long NBAR = T_;
  const long total = NX + NWIH + NWHH + NBS + NBAR;
  for (long q = (long)blockIdx.x * blockDim.x + threadIdx.x; q < total;
       q += (long)gridDim.x * blockDim.x) {
    long r = q;
    if (r < NX) {
      int t = (int)(r / (B_ * EP));
      int rem = (int)(r % (B_ * EP));
      int b = rem / EP, e = rem % EP;
      float v = (e < E_) ? x[((long)b * T_ + t) * E_ + e] : 0.0f;
      xbf[r] = f2bf(v);
    } else if ((r -= NX) < NWIH) {
      int n = (int)(r / EP), e = (int)(r % EP);
      wihb[r] = f2bf((e < E_) ? Wih[(long)n * E_ + e] : 0.0f);
    } else if ((r -= NWIH) < NWHH) {
      whhb[r] = f2bf(Whh[r]);   // [8192,2048] row-major == B^T layout
    } else if ((r -= NWHH) < NBS) {
      biasc[r] = bih[r] + bhh[r];
    } else {
      r -= NBS;
      bar[r] = 0;               // visible after kernel-end flush
    }
  }
}

// ---------------- main persistent LSTM kernel ----------------
// 256 blocks x 256 thr, 1 block/CU. Block: 64 batch rows x (32 j-cols x 4 gates).
// Same tiling/XCD mapping/coherence as the verified 3.78ms kernel. Change:
// 4-deep staging pipeline with counted s_waitcnt vmcnt(N) + raw s_barrier
// (T3+T4) instead of double-buffer + __syncthreads (which drains vmcnt(0)
// every chunk and exposes one full load latency per chunk = 780ns). Up to 3
// chunks (18 GLDS instr/wave) stay in flight across barriers.
__global__ void __launch_bounds__(256, 1)
lstm_kernel(const u16* __restrict__ xbf, const u16* __restrict__ wihb,
            const u16* __restrict__ whhb, const float* __restrict__ biasc,
            u16* __restrict__ hbuf, u32* __restrict__ bar, float* __restrict__ out) {
  __shared__ __align__(16) u16 As[4][64 * 64];    // 32 KB: A tiles 64 rows x 64 k
  __shared__ __align__(16) u16 Bs[4][128 * 64];   // 64 KB: B tiles 128 n x 64 k

  const int tid = threadIdx.x;
  const int l = tid & 63;
  const int w = tid >> 6;
  const int wr = w >> 1, wj = w & 1;       // wave tile: 32 rows x (16 j x 4 gates)
  const int bid = blockIdx.x;
  const int b0 = (bid >> 6) << 6;
  const int j0 = (bid & 63) << 5;
  const int jc = j0 + (wj << 4) + (l & 15);
  // XOR-swizzle: LDS slot (row, c) holds global chunk c ^ (row&7); conflict-free b128.
  const int cgl = (tid & 7) ^ ((tid >> 3) & 7);

  const float bi = biasc[jc];
  const float bff = biasc[2048 + jc];
  const float bg = biasc[4096 + jc];
  const float bo = biasc[6144 + jc];

  float cst[2][4];
#pragma unroll
  for (int mi = 0; mi < 2; ++mi)
#pragma unroll
    for (int r = 0; r < 4; ++r) cst[mi][r] = 0.0f;

  // A: 8 KB = 2 issues x 256 thr x 16 B ; rows are batch-local 0..63
  auto stageA = [&](const u16* srcA, int strA, int kk, int p, bool coh) {
    u16* Ad = &As[p][w * 512];
#pragma unroll
    for (int i = 0; i < 2; ++i) {
      int slot = i * 256 + tid;
      const u16* g = srcA + (size_t)(slot >> 3) * strA + kk + cgl * 8;
      if (coh) { GLDS16C(g, Ad + i * 2048); } else { GLDS16(g, Ad + i * 2048); }
    }
  };
  // B: 16 KB = 4 issues ; LDS row nl = gate*32 + jj -> global row gate*2048 + j0 + jj
  auto stageB = [&](const u16* srcB, int strB, int kk, int p) {
    u16* Bd = &Bs[p][w * 512];
#pragma unroll
    for (int i = 0; i < 4; ++i) {
      int slot = i * 256 + tid;
      int nl = slot >> 3;
      int grow = ((nl >> 5) << 11) + j0 + (nl & 31);
      const u16* g = srcB + (size_t)grow * strB + kk + cgl * 8;
      GLDS16(g, Bd + i * 2048);
    }
  };

  // leading edge: my loads for the chunk I'm about to read are complete
  // (counted vmcnt - newer prefetches stay in flight), then all waves align.
  auto lead = [&](int vm) {
    switch (vm) {
      case 18: asm volatile("s_waitcnt vmcnt(18)" ::: "memory"); break;
      case 14: asm volatile("s_waitcnt vmcnt(14)" ::: "memory"); break;
      case 12: asm volatile("s_waitcnt vmcnt(12)" ::: "memory"); break;
      case 10: asm volatile("s_waitcnt vmcnt(10)" ::: "memory"); break;
      case 6:  asm volatile("s_waitcnt vmcnt(6)"  ::: "memory"); break;
      default: asm volatile("s_waitcnt vmcnt(0)"  ::: "memory"); break;
    }
    __builtin_amdgcn_s_barrier();
    __builtin_amdgcn_sched_barrier(0);
  };
  // trailing edge: my ds_reads done, then all waves done reading this buffer
  // (so the next stage may overwrite it). No vmcnt drain.
  auto trail = [&]() {
    asm volatile("s_waitcnt lgkmcnt(0)" ::: "memory");
    __builtin_amdgcn_sched_barrier(0);
    __builtin_amdgcn_s_barrier();
  };

#pragma unroll 1
  for (int t = 0; t < T_; ++t) {
    const u16* hcur = hbuf + (size_t)(t & 1) * (B_ * H_) + (size_t)b0 * H_;
    u16* hnxt = hbuf + (size_t)((t + 1) & 1) * (B_ * H_);
    const u16* xsrc = xbf + (size_t)t * (B_ * EP) + (size_t)b0 * EP;

    f32x4 acc[2][4];
#pragma unroll
    for (int mi = 0; mi < 2; ++mi)
#pragma unroll
      for (int g = 0; g < 4; ++g) acc[mi][g] = (f32x4){0.f, 0.f, 0.f, 0.f};

    auto compute = [&](int p) {
#pragma unroll
      for (int k2 = 0; k2 < 2; ++k2) {
        int cp = ((k2 << 2) + (l >> 4)) ^ (l & 7);    // swizzled chunk (row&7 == l&7)
        const u16* ap = &As[p][((wr << 5) + (l & 15)) * 64 + cp * 8];
        bf16x8 a0 = *(const bf16x8*)ap;
        bf16x8 a1 = *(const bf16x8*)(ap + 1024);      // +16 rows
        const u16* bp = &Bs[p][((wj << 4) + (l & 15)) * 64 + cp * 8];
        bf16x8 bv0 = *(const bf16x8*)bp;
        bf16x8 bv1 = *(const bf16x8*)(bp + 2048);     // +32 n-rows = next gate
        bf16x8 bv2 = *(const bf16x8*)(bp + 4096);
        bf16x8 bv3 = *(const bf16x8*)(bp + 6144);
        acc[0][0] = __builtin_amdgcn_mfma_f32_16x16x32_bf16(a0, bv0, acc[0][0], 0, 0, 0);
        acc[0][1] = __builtin_amdgcn_mfma_f32_16x16x32_bf16(a0, bv1, acc[0][1], 0, 0, 0);
        acc[0][2] = __builtin_amdgcn_mfma_f32_16x16x32_bf16(a0, bv2, acc[0][2], 0, 0, 0);
        acc[0][3] = __builtin_amdgcn_mfma_f32_16x16x32_bf16(a0, bv3, acc[0][3], 0, 0, 0);
        acc[1][0] = __builtin_amdgcn_mfma_f32_16x16x32_bf16(a1, bv0, acc[1][0], 0, 0, 0);
        acc[1][1] = __builtin_amdgcn_mfma_f32_16x16x32_bf16(a1, bv1, acc[1][1], 0, 0, 0);
        acc[1][2] = __builtin_amdgcn_mfma_f32_16x16x32_bf16(a1, bv2, acc[1][2], 0, 0, 0);
        acc[1][3] = __builtin_amdgcn_mfma_f32_16x16x32_bf16(a1, bv3, acc[1][3], 0, 0, 0);
      }
    };

    // ---- x phase: 5 chunks, 4-buffer pipeline, fully unrolled.
    // prologue: chunks 0..2
    stageA(xsrc, EP, 0, 0, false);   stageB(wihb, EP, 0, 0);
    stageA(xsrc, EP, 64, 1, false);  stageB(wihb, EP, 64, 1);
    stageA(xsrc, EP, 128, 2, false); stageB(wihb, EP, 128, 2);
    // k=0 (stage 3)
    stageA(xsrc, EP, 192, 3, false); stageB(wihb, EP, 192, 3);
    lead(18); compute(0); trail();
    // k=1 (stage 4 -> buf0)
    stageA(xsrc, EP, 256, 0, false); stageB(wihb, EP, 256, 0);
    lead(18); compute(1); trail();
    // k=2..4 (drain)
    lead(12); compute(2); trail();
    lead(6);  compute(3); trail();
    lead(0);  compute(0); trail();

    // ---- h phase (skipped at t=0: h==0)
    if (t > 0) {
      // W_hh B-prefetch for chunks 0..2 BEFORE the spin (no h dependency):
      // loads fly while we wait for producers.
      stageB(whhb, H_, 0, 0);
      stageB(whhb, H_, 64, 1);
      stageB(whhb, H_, 128, 2);
      if (tid == 0) {
        while (__hip_atomic_load(&bar[t - 1], __ATOMIC_RELAXED,
                                 __HIP_MEMORY_SCOPE_AGENT) < 256u)
          __builtin_amdgcn_s_sleep(2);
      }
      __syncthreads();
      // A (h) prologue: chunks 0..2
      stageA(hcur, H_, 0, 0, true);
      stageA(hcur, H_, 64, 1, true);
      stageA(hcur, H_, 128, 2, true);
#pragma unroll 1
      for (int kh = 0; kh < 32; ++kh) {
        if (kh < 29) {
          stageA(hcur, H_, (kh + 3) << 6, (kh + 3) & 3, true);
          stageB(whhb, H_, (kh + 3) << 6, (kh + 3) & 3);
        }
        // instrs issued after chunk kh's last load (A=2,B=4 per chunk):
        // kh=0: A1,A2 + s3 = 10 ; kh=1: A2 + s3,s4 = 14 ; steady: 3 chunks = 18
        // tail: kh=29:12, 30:6, 31:0
        int vm = (kh == 0) ? 10 : (kh == 1) ? 14 : (kh < 29) ? 18 : (31 - kh) * 6;
        lead(vm);
        compute(kh & 3);
        trail();
      }
    }

    // ---- lane-local LSTM pointwise; c stays in registers across steps
#pragma unroll
    for (int mi = 0; mi < 2; ++mi) {
#pragma unroll
      for (int r = 0; r < 4; ++r) {
        float ig = sigm_f(acc[mi][0][r] + bi);
        float fg = sigm_f(acc[mi][1][r] + bff);
        float gg = tanh_f(acc[mi][2][r] + bg);
        float og = sigm_f(acc[mi][3][r] + bo);
        float c = fg * cst[mi][r] + ig * gg;
        cst[mi][r] = c;
        float h = og * tanh_f(c);
        int row = b0 + (wr << 5) + (mi << 4) + ((l >> 4) << 2) + r;
        if (t < T_ - 1) {
          u16 hv = f2bf(h);
          u16* hp = hnxt + (size_t)row * H_ + jc;
          asm volatile("global_store_short %0, %1, off sc0 sc1"
                       :: "v"(hp), "v"((u32)hv) : "memory");
        } else {
          out[(size_t)row * H_ + jc] = h;
        }
      }
    }

    if (t < T_ - 1) {
      __builtin_amdgcn_s_waitcnt(0);      // h stores reached coherent point
      __syncthreads();                    // all 4 waves drained
      if (tid == 0)
        __hip_atomic_fetch_add(&bar[t], 1u, __ATOMIC_RELAXED,
                               __HIP_MEMORY_SCOPE_AGENT);
    }
  }
}

extern "C" void kernel_launch(void* const* d_in, const int* in_sizes, int n_in,
                              void* d_out, int out_size, void* d_ws, size_t ws_size,
                              hipStream_t stream) {
  const float* x = (const float*)d_in[0];
  const float* Wih = (const float*)d_in[1];
  const float* Whh = (const float*)d_in[2];
  const float* bih = (const float*)d_in[3];
  const float* bhh = (const float*)d_in[4];
  char* ws = (char*)d_ws;
  u16* xbf = (u16*)(ws + OFF_XBF);
  u16* wihb = (u16*)(ws + OFF_WIH);
  u16* whhb = (u16*)(ws + OFF_WHH);
  float* biasc = (float*)(ws + OFF_BIAS);
  u16* hbuf = (u16*)(ws + OFF_HBUF);
  u32* bar = (u32*)(ws + OFF_BAR);
  float* out = (float*)d_out;

  hipLaunchKernelGGL(prep_kernel, dim3(2048), dim3(256), 0, stream,
                     x, Wih, Whh, bih, bhh, xbf, wihb, whhb, biasc, bar);

  void* args[] = {(void*)&xbf, (void*)&wihb, (void*)&whhb,
                  (void*)&biasc, (void*)&hbuf, (void*)&bar, (void*)&out};
  hipLaunchCooperativeKernel((void*)lstm_kernel, dim3(256), dim3(256), args, 0, stream);
}

// Round 4
// 3629.160 us; speedup vs baseline: 1.9923x; 1.0271x over previous
//
#include <hip/hip_runtime.h>

typedef unsigned short u16;
typedef unsigned int u32;
typedef __bf16 bf16x8 __attribute__((ext_vector_type(8)));
typedef float f32x4 __attribute__((ext_vector_type(4)));

#define B_ 256
#define T_ 128
#define E_ 300
#define EP 320
#define H_ 2048
#define G_ 8192

// ws layout (bytes)
#define OFF_XBF   0UL
#define OFF_WIH   20971520UL
#define OFF_WHH   26214400UL
#define OFF_BIAS  59768832UL
#define OFF_HBUF  59801600UL
#define OFF_BAR   61898752UL

// plain global->LDS (L2-cacheable: weights, x)
#define GLDS16(gp, sp)                                                    \
  __builtin_amdgcn_global_load_lds(                                       \
      (__attribute__((address_space(1))) void*)(void*)(gp),               \
      (__attribute__((address_space(3))) void*)(sp), 16, 0, 0)
// device-coherent global->LDS (sc0|sc1 = 1|16: bypass L1+L2) for h
#define GLDS16C(gp, sp)                                                   \
  __builtin_amdgcn_global_load_lds(                                       \
      (__attribute__((address_space(1))) void*)(void*)(gp),               \
      (__attribute__((address_space(3))) void*)(sp), 16, 0, 17)

__device__ __forceinline__ u16 f2bf(float f) {
  u32 u = __builtin_bit_cast(u32, f);
  return (u16)((u + 0x7FFFu + ((u >> 16) & 1u)) >> 16);
}
__device__ __forceinline__ float sigm_f(float x) {
  return __builtin_amdgcn_rcpf(1.0f + __expf(-x));
}
__device__ __forceinline__ float tanh_f(float x) {
  return 1.0f - 2.0f * __builtin_amdgcn_rcpf(1.0f + __expf(2.0f * x));
}

// ---------------- prep: pack/convert to bf16, zero barrier flags ----------------
__global__ void prep_kernel(const float* __restrict__ x, const float* __restrict__ Wih,
                            const float* __restrict__ Whh, const float* __restrict__ bih,
                            const float* __restrict__ bhh, u16* __restrict__ xbf,
                            u16* __restrict__ wihb, u16* __restrict__ whhb,
                            float* __restrict__ biasc, u32* __restrict__ bar) {
  const long NX = (long)T_ * B_ * EP;
  const long NWIH = (long)G_ * EP;
  const long NWHH = (long)G_ * H_;
  const long NBS = G_;
  const long NBAR = T_;
  const long total = NX + NWIH + NWHH + NBS + NBAR;
  for (long q = (long)blockIdx.x * blockDim.x + threadIdx.x; q < total;
       q += (long)gridDim.x * blockDim.x) {
    long r = q;
    if (r < NX) {
      int t = (int)(r / (B_ * EP));
      int rem = (int)(r % (B_ * EP));
      int b = rem / EP, e = rem % EP;
      float v = (e < E_) ? x[((long)b * T_ + t) * E_ + e] : 0.0f;
      xbf[r] = f2bf(v);
    } else if ((r -= NX) < NWIH) {
      int n = (int)(r / EP), e = (int)(r % EP);
      wihb[r] = f2bf((e < E_) ? Wih[(long)n * E_ + e] : 0.0f);
    } else if ((r -= NWIH) < NWHH) {
      whhb[r] = f2bf(Whh[r]);   // [8192,2048] row-major == B^T layout
    } else if ((r -= NWHH) < NBS) {
      biasc[r] = bih[r] + bhh[r];
    } else {
      r -= NBS;
      bar[r] = 0;               // visible after kernel-end flush
    }
  }
}

// ---------------- main persistent LSTM kernel ----------------
// 256 blocks x 512 thr (8 waves), 1 block/CU = 2 waves/SIMD (TLP: while one
// wave stalls at vmcnt/ds_read, its SIMD-mate computes -- m114 overlap).
// Block: 64 batch rows x (32 j-cols x 4 gates); wave: 16 rows x (16 j x 4 g).
// Same XCD mapping / sc0sc1 h coherence / atomic-counter step barrier as the
// verified R2 kernel. 4-buffer counted-vmcnt pipeline, 3 VMEM instr/chunk/wave.
__global__ void __launch_bounds__(512, 2)
lstm_kernel(const u16* __restrict__ xbf, const u16* __restrict__ wihb,
            const u16* __restrict__ whhb, const float* __restrict__ biasc,
            u16* __restrict__ hbuf, u32* __restrict__ bar, float* __restrict__ out) {
  __shared__ __align__(16) u16 As[4][64 * 64];    // 32 KB: A tiles 64 rows x 64 k
  __shared__ __align__(16) u16 Bs[4][128 * 64];   // 64 KB: B tiles 128 n x 64 k

  const int tid = threadIdx.x;
  const int l = tid & 63;
  const int w = tid >> 6;                  // 8 waves
  const int wr = w >> 1, wj = w & 1;       // wave tile: 16 rows x (16 j x 4 gates)
  const int bid = blockIdx.x;
  const int b0 = (bid >> 6) << 6;
  const int j0 = (bid & 63) << 5;
  const int jc = j0 + (wj << 4) + (l & 15);
  // XOR-swizzle: LDS slot (row, c) holds global chunk c ^ (row&7); conflict-free b128.
  const int cgl = (tid & 7) ^ ((tid >> 3) & 7);

  const float bi = biasc[jc];
  const float bff = biasc[2048 + jc];
  const float bg = biasc[4096 + jc];
  const float bo = biasc[6144 + jc];

  float cst[4];
#pragma unroll
  for (int r = 0; r < 4; ++r) cst[r] = 0.0f;

  // A: 8 KB = 1 issue x 512 thr x 16 B ; rows are batch-local 0..63
  auto stageA = [&](const u16* srcA, int strA, int kk, int p, bool coh) {
    u16* Ad = &As[p][w * 512];
    const u16* g = srcA + (size_t)(tid >> 3) * strA + kk + cgl * 8;
    if (coh) { GLDS16C(g, Ad); } else { GLDS16(g, Ad); }
  };
  // B: 16 KB = 2 issues ; LDS row nl = gate*32 + jj -> global row gate*2048 + j0 + jj
  auto stageB = [&](const u16* srcB, int strB, int kk, int p) {
    u16* Bd = &Bs[p][w * 512];
#pragma unroll
    for (int i = 0; i < 2; ++i) {
      int slot = i * 512 + tid;
      int nl = slot >> 3;
      int grow = ((nl >> 5) << 11) + j0 + (nl & 31);
      const u16* g = srcB + (size_t)grow * strB + kk + cgl * 8;
      GLDS16(g, Bd + i * 4096);
    }
  };

  // leading edge: chunk-to-read complete (counted vmcnt: newer prefetches stay
  // in flight), then all waves align.
  auto lead = [&](int vm) {
    switch (vm) {
      case 9: asm volatile("s_waitcnt vmcnt(9)" ::: "memory"); break;
      case 7: asm volatile("s_waitcnt vmcnt(7)" ::: "memory"); break;
      case 6: asm volatile("s_waitcnt vmcnt(6)" ::: "memory"); break;
      case 5: asm volatile("s_waitcnt vmcnt(5)" ::: "memory"); break;
      case 3: asm volatile("s_waitcnt vmcnt(3)" ::: "memory"); break;
      default: asm volatile("s_waitcnt vmcnt(0)" ::: "memory"); break;
    }
    __builtin_amdgcn_s_barrier();
    __builtin_amdgcn_sched_barrier(0);
  };
  // trailing edge: my ds_reads done, then all waves done reading this buffer.
  auto trail = [&]() {
    asm volatile("s_waitcnt lgkmcnt(0)" ::: "memory");
    __builtin_amdgcn_sched_barrier(0);
    __builtin_amdgcn_s_barrier();
  };

#pragma unroll 1
  for (int t = 0; t < T_; ++t) {
    const u16* hcur = hbuf + (size_t)(t & 1) * (B_ * H_) + (size_t)b0 * H_;
    u16* hnxt = hbuf + (size_t)((t + 1) & 1) * (B_ * H_);
    const u16* xsrc = xbf + (size_t)t * (B_ * EP) + (size_t)b0 * EP;

    f32x4 acc[4];
#pragma unroll
    for (int g = 0; g < 4; ++g) acc[g] = (f32x4){0.f, 0.f, 0.f, 0.f};

    auto compute = [&](int p) {
#pragma unroll
      for (int k2 = 0; k2 < 2; ++k2) {
        int cp = ((k2 << 2) + (l >> 4)) ^ (l & 7);    // swizzled chunk (row&7 == l&7)
        const u16* ap = &As[p][((wr << 4) + (l & 15)) * 64 + cp * 8];
        bf16x8 a0 = *(const bf16x8*)ap;
        const u16* bp = &Bs[p][((wj << 4) + (l & 15)) * 64 + cp * 8];
        bf16x8 bv0 = *(const bf16x8*)bp;
        bf16x8 bv1 = *(const bf16x8*)(bp + 2048);     // +32 n-rows = next gate
        bf16x8 bv2 = *(const bf16x8*)(bp + 4096);
        bf16x8 bv3 = *(const bf16x8*)(bp + 6144);
        acc[0] = __builtin_amdgcn_mfma_f32_16x16x32_bf16(a0, bv0, acc[0], 0, 0, 0);
        acc[1] = __builtin_amdgcn_mfma_f32_16x16x32_bf16(a0, bv1, acc[1], 0, 0, 0);
        acc[2] = __builtin_amdgcn_mfma_f32_16x16x32_bf16(a0, bv2, acc[2], 0, 0, 0);
        acc[3] = __builtin_amdgcn_mfma_f32_16x16x32_bf16(a0, bv3, acc[3], 0, 0, 0);
      }
    };

    // ---- x phase: 5 chunks, 4-buffer pipeline, fully unrolled. 3 instr/chunk.
    stageA(xsrc, EP, 0, 0, false);   stageB(wihb, EP, 0, 0);
    stageA(xsrc, EP, 64, 1, false);  stageB(wihb, EP, 64, 1);
    stageA(xsrc, EP, 128, 2, false); stageB(wihb, EP, 128, 2);
    stageA(xsrc, EP, 192, 3, false); stageB(wihb, EP, 192, 3);
    lead(9); compute(0); trail();                     // out 12 -> wait c0
    stageA(xsrc, EP, 256, 0, false); stageB(wihb, EP, 256, 0);
    lead(9); compute(1); trail();                     // out 12 -> wait c1
    lead(6); compute(2); trail();                     // out 9  -> wait c2
    lead(3); compute(3); trail();                     // out 6  -> wait c3
    lead(0); compute(0); trail();                     // out 3  -> wait c4

    // ---- h phase (skipped at t=0: h==0)
    if (t > 0) {
      // W_hh B-prefetch for chunks 0..2 BEFORE the spin (no h dependency):
      // loads fly while we wait for producers. 2 instr each.
      stageB(whhb, H_, 0, 0);
      stageB(whhb, H_, 64, 1);
      stageB(whhb, H_, 128, 2);
      // wave-0 spin drains its own vmcnt (atomic load) -- only strengthens its
      // waits; ledger below is exact for the non-spinning waves and the kh=0
      // wait equalizes both classes at 5 outstanding.
      if (tid == 0) {
        while (__hip_atomic_load(&bar[t - 1], __ATOMIC_RELAXED,
                                 __HIP_MEMORY_SCOPE_AGENT) < 256u)
          __builtin_amdgcn_s_sleep(2);
      }
      __syncthreads();
      // A (h) prologue: chunks 0..2
      stageA(hcur, H_, 0, 0, true);
      stageA(hcur, H_, 64, 1, true);
      stageA(hcur, H_, 128, 2, true);
#pragma unroll 1
      for (int kh = 0; kh < 32; ++kh) {
        if (kh < 29) {
          stageA(hcur, H_, (kh + 3) << 6, (kh + 3) & 3, true);
          stageB(whhb, H_, (kh + 3) << 6, (kh + 3) & 3);
        }
        // issue order: B0 B1 B2 | A0 A1 A2 | per-kh {A,B}. newest of chunk kh
        // is A(kh) for kh<3 (its B is in the pre-spin batch), else B(kh).
        // kh=0: out 12, newer-than-A0 = 5 ; kh=1: out 8, newer = 7 ;
        // kh=2: out 10, newer = 9 ; kh=3..28 steady: out 12, newer = 9 ;
        // kh=29: out 9 -> 6 ; kh=30: out 6 -> 3 ; kh=31: out 3 -> 0.
        int vm = (kh == 0) ? 5 : (kh == 1) ? 7 : (kh < 29) ? 9
               : (kh == 29) ? 6 : (kh == 30) ? 3 : 0;
        lead(vm);
        compute(kh & 3);
        trail();
      }
    }

    // ---- lane-local LSTM pointwise; c stays in registers across steps
#pragma unroll
    for (int r = 0; r < 4; ++r) {
      float ig = sigm_f(acc[0][r] + bi);
      float fg = sigm_f(acc[1][r] + bff);
      float gg = tanh_f(acc[2][r] + bg);
      float og = sigm_f(acc[3][r] + bo);
      float c = fg * cst[r] + ig * gg;
      cst[r] = c;
      float h = og * tanh_f(c);
      int row = b0 + (wr << 4) + ((l >> 4) << 2) + r;
      if (t < T_ - 1) {
        u16 hv = f2bf(h);
        u16* hp = hnxt + (size_t)row * H_ + jc;
        asm volatile("global_store_short %0, %1, off sc0 sc1"
                     :: "v"(hp), "v"((u32)hv) : "memory");
      } else {
        out[(size_t)row * H_ + jc] = h;
      }
    }

    if (t < T_ - 1) {
      __builtin_amdgcn_s_waitcnt(0);      // h stores reached coherent point
      __syncthreads();                    // all 8 waves drained
      if (tid == 0)
        __hip_atomic_fetch_add(&bar[t], 1u, __ATOMIC_RELAXED,
                               __HIP_MEMORY_SCOPE_AGENT);
    }
  }
}

extern "C" void kernel_launch(void* const* d_in, const int* in_sizes, int n_in,
                              void* d_out, int out_size, void* d_ws, size_t ws_size,
                              hipStream_t stream) {
  const float* x = (const float*)d_in[0];
  const float* Wih = (const float*)d_in[1];
  const float* Whh = (const float*)d_in[2];
  const float* bih = (const float*)d_in[3];
  const float* bhh = (const float*)d_in[4];
  char* ws = (char*)d_ws;
  u16* xbf = (u16*)(ws + OFF_XBF);
  u16* wihb = (u16*)(ws + OFF_WIH);
  u16* whhb = (u16*)(ws + OFF_WHH);
  float* biasc = (float*)(ws + OFF_BIAS);
  u16* hbuf = (u16*)(ws + OFF_HBUF);
  u32* bar = (u32*)(ws + OFF_BAR);
  float* out = (float*)d_out;

  hipLaunchKernelGGL(prep_kernel, dim3(2048), dim3(256), 0, stream,
                     x, Wih, Whh, bih, bhh, xbf, wihb, whhb, biasc, bar);

  void* args[] = {(void*)&xbf, (void*)&wihb, (void*)&whhb,
                  (void*)&biasc, (void*)&hbuf, (void*)&bar, (void*)&out};
  hipLaunchCooperativeKernel((void*)lstm_kernel, dim3(256), dim3(512), args, 0, stream);
}